// Round 4
// baseline (286.943 us; speedup 1.0000x reference)
//
#include <hip/hip_runtime.h>

// Multires hash-grid encode (2D, instant-NGP style). Round 7: FUSED.
//
// Round-6 evidence killed the two-pass design:
//  - level_pass is gather-TRANSACTION-throughput-bound (2x MLP: no effect;
//    VALU 10%, HBM 18%, occ 76% -> every pipe idle, TA/TCP saturated).
//  - FETCH=133 MiB decomposes as 64 MiB of x RE-READS (level-major reads x
//    once per level) + ~49 MiB tables + misc. Structure-inflicted traffic.
//  - transpose_out pinned at ~93 us across 3 layouts + a 128 MiB ws
//    round-trip that exists only to serve the level-major split.
// Fused kernel: block = 256 points; thread = 1 point x 16 levels in
// registers (x read ONCE, 64-deep gather MLP, no barriers in the gather
// phase), then the proven stride-257 LDS transpose -> coalesced nt float4
// stores. ws/out streaming gone -> tables (44.8 MiB) stay L3-resident.
// Index math bit-exact vs the jax reference (32-bit hash residue proof in
// prep_level). nt stores keep `out` from evicting tables.

static constexpr int  kPoints    = 524288;
static constexpr int  kLevels    = 16;
static constexpr int  kStartHash = 6;
static constexpr unsigned kPs1     = 19349663u;
static constexpr unsigned kEntries = 524309u;
static constexpr unsigned kR32     = 352277u;   // 2^32 mod kEntries

typedef float v4f __attribute__((ext_vector_type(4)));

__device__ __forceinline__ void nt_store4(float4* p, const float4 v) {
    v4f t; t.x = v.x; t.y = v.y; t.z = v.z; t.w = v.w;
    __builtin_nontemporal_store(t, (v4f*)p);
}

__constant__ unsigned c_level_off[kLevels] = {
    0u, 289u, 1378u, 5603u, 22244u, 88293u, 351462u,
    875771u, 1400080u, 1924389u, 2448698u, 2973007u,
    3497316u, 4021625u, 4545934u, 5070243u
};

struct Corners {
    float    w00, w01, w10, w11;
    unsigned i00, i01, i10, i11;   // absolute table indices (level base folded in)
};

__device__ __forceinline__ Corners prep_level(const float2 p, const int l)
{
    const int   scale_i = 16 << l;
    const float scale_f = (float)scale_i;

    const float fx = p.x * scale_f;
    const float fy = p.y * scale_f;

    // coords in [0,1) -> indices nonnegative, max 524288 at level 15: u32 ok.
    const unsigned ix0 = (unsigned)(int)fx;
    const unsigned iy0 = (unsigned)(int)fy;
    const unsigned ix1 = (unsigned)(int)(fx + 1.0f);   // NOT always ix0+1 (fp rounding)
    const unsigned iy1 = (unsigned)(int)(fy + 1.0f);

    const float ox = fx - (float)ix0;
    const float oy = fy - (float)iy0;

    const float wx1 = fminf(fmaxf(ox, 0.0f), 1.0f);
    const float wx0 = fminf(fmaxf(1.0f - ox, 0.0f), 1.0f);
    const float wy1 = fminf(fmaxf(oy, 0.0f), 1.0f);
    const float wy0 = fminf(fmaxf(1.0f - oy, 0.0f), 1.0f);

    unsigned i00, i01, i10, i11;
    if (l < kStartHash) {
        const unsigned stride = (unsigned)(scale_i + 1);
        i00 = ix0 * stride + iy0;
        i01 = ix0 * stride + iy1;
        i10 = ix1 * stride + iy0;
        i11 = ix1 * stride + iy1;
    } else {
        // 32-bit replication of ((ix ^ (iy*PS1)) % E), bit-exact vs int64:
        // hy = iy*PS1 = hi*2^32+lo, hi <= 2362, ix < 2^20 so xor touches lo only.
        // (hi*2^32 + (lo^ix)) % E = ((hi*R32)%E + (lo^ix)%E) cond-sub E.
        const unsigned long long hy0 = (unsigned long long)iy0 * kPs1;
        const unsigned long long hy1 = (unsigned long long)iy1 * kPs1;
        const unsigned lo0 = (unsigned)hy0, hi0 = (unsigned)(hy0 >> 32);
        const unsigned lo1 = (unsigned)hy1, hi1 = (unsigned)(hy1 >> 32);
        const unsigned a0 = (hi0 * kR32) % kEntries;   // hi*R32 < 2^30
        const unsigned a1 = (hi1 * kR32) % kEntries;
        i00 = a0 + ((lo0 ^ ix0) % kEntries); if (i00 >= kEntries) i00 -= kEntries;
        i01 = a1 + ((lo1 ^ ix0) % kEntries); if (i01 >= kEntries) i01 -= kEntries;
        i10 = a0 + ((lo0 ^ ix1) % kEntries); if (i10 >= kEntries) i10 -= kEntries;
        i11 = a1 + ((lo1 ^ ix1) % kEntries); if (i11 >= kEntries) i11 -= kEntries;
    }

    Corners c;
    const unsigned base = c_level_off[l];
    c.i00 = base + i00; c.i01 = base + i01;
    c.i10 = base + i10; c.i11 = base + i11;
    c.w00 = wx0 * wy0;  c.w01 = wx0 * wy1;
    c.w10 = wx1 * wy0;  c.w11 = wx1 * wy1;
    return c;
}

__device__ __forceinline__ float2 finish_level(
    const Corners& c, const float2* __restrict__ tbl)
{
    const float2 v00 = tbl[c.i00];
    const float2 v01 = tbl[c.i01];
    const float2 v10 = tbl[c.i10];
    const float2 v11 = tbl[c.i11];
    return make_float2(
        c.w00 * v00.x + c.w01 * v01.x + c.w10 * v10.x + c.w11 * v11.x,
        c.w00 * v00.y + c.w01 * v01.y + c.w10 * v10.y + c.w11 * v11.y);
}

// ---- Fused: gather all 16 levels in registers, LDS-transpose, nt store --
static constexpr int kTStride = 257;  // float2 elems per level row in LDS

__global__ __launch_bounds__(256) void fused_pass(
    const float2* __restrict__ x,
    const float2* __restrict__ tbl,
    float4* __restrict__ out)
{
    __shared__ float2 lds[kLevels * kTStride];  // ~32.9 KB -> 4 blocks/CU

    const int t = threadIdx.x;
    const int n = (blockIdx.x << 8) | t;
    const float2 p = x[n];          // x read exactly once per point

    // All 16 levels in registers; full unroll -> 64 independent gathers,
    // compiler pipelines address calc + loads across levels (deep MLP).
    float2 r[kLevels];
#pragma unroll
    for (int l = 0; l < kLevels; ++l)
        r[l] = finish_level(prep_level(p, l), tbl);

#pragma unroll
    for (int l = 0; l < kLevels; ++l)
        lds[l * kTStride + t] = r[l];

    __syncthreads();

    // out[n][32 floats]: 8 coalesced float4 stores per thread (proven in
    // round-4 transpose: stride-257 LDS rows, 0 bank conflicts measured).
    float4* o = out + ((size_t)blockIdx.x << 11);   // 256 pts * 8 float4
#pragma unroll
    for (int k = 0; k < 8; ++k) {
        const int f  = k * 256 + t;
        const int nl = f >> 3;       // local point
        const int i  = t & 7;        // float4 index within the 32-float row
        const float2 a = lds[(2 * i)     * kTStride + nl];
        const float2 b = lds[(2 * i + 1) * kTStride + nl];
        nt_store4(&o[f], make_float4(a.x, a.y, b.x, b.y));
    }
}

extern "C" void kernel_launch(void* const* d_in, const int* in_sizes, int n_in,
                              void* d_out, int out_size, void* d_ws, size_t ws_size,
                              hipStream_t stream) {
    const float2* x   = (const float2*)d_in[0];
    const float2* tbl = (const float2*)d_in[1];
    fused_pass<<<kPoints / 256, 256, 0, stream>>>(x, tbl, (float4*)d_out);
}